// Round 11
// baseline (508.326 us; speedup 1.0000x reference)
//
#include <hip/hip_runtime.h>
#include <hip/hip_bf16.h>
#include <cstdint>
#include <cstddef>

typedef __bf16 bf16;
typedef __bf16 bf16x4 __attribute__((ext_vector_type(4)));
typedef __bf16 bf16x8 __attribute__((ext_vector_type(8)));
typedef float  f32x4  __attribute__((ext_vector_type(4)));
typedef float  f32x8  __attribute__((ext_vector_type(8)));

#define MB   8192
#define NN   4096
#define RR   16
#define KOUT 4096

#define FENCE() asm volatile("" ::: "memory")
#define BARRIER() do { FENCE(); __builtin_amdgcn_s_barrier(); FENCE(); } while (0)

// ---------------------------------------------------------------------------
// async global->LDS (16B per lane). LDS dest: wave-uniform base + lane*16.
__device__ __forceinline__ void gload_lds16(const bf16* g, bf16* l) {
  __builtin_amdgcn_global_load_lds(
      (const __attribute__((address_space(1))) void*)g,
      (__attribute__((address_space(3))) void*)l, 16, 0, 0);
}

// ---------------------------------------------------------------------------
// Single prologue dispatch.
//  blocks [0,2048):    4 x-rows each: xh = x@H^T computed LOCALLY (f32 VALU,
//                      lane=(row,r), wave=k-slice, LDS reduce) then
//                      h = relu(xh@G + b1) -> bf16.  No cross-block deps.
//  blocks [2048,6144): W2t[o][n] = (bf16)W2[n][o] (64x64 LDS tile).
__global__ __launch_bounds__(256) void d_pre(
    const float* __restrict__ x, const float* __restrict__ H,
    const float* __restrict__ G, const float* __restrict__ b1,
    bf16* __restrict__ hout,
    const float* __restrict__ W2, bf16* __restrict__ W2t)
{
  __shared__ float red[4][64];     // role-h wave partials (1 KB)
  __shared__ float sS[4][16];      // role-h xh tile
  __shared__ float tile[64][65];   // role-w2t (16.6 KB)
  const int t = threadIdx.x;

  if (blockIdx.x < 2048) {
    // ---- phase A: xh[4][16] for rows r0..r0+3, pure f32.
    const int r0   = blockIdx.x * 4;
    const int lane = t & 63, w = t >> 6;
    const int row  = lane >> 4;      // 0..3  (x row)
    const int r    = lane & 15;      // 0..15 (H row)
    const float* xp = x + (size_t)(r0 + row) * NN + w * 1024;
    const float* hp = H + (size_t)r * NN + w * 1024;

    f32x4 acc4 = {0.f, 0.f, 0.f, 0.f};
#pragma unroll 8
    for (int k = 0; k < 1024; k += 4) {
      const f32x4 xv = *(const f32x4*)(xp + k);
      const f32x4 hv = *(const f32x4*)(hp + k);
      acc4 += xv * hv;
    }
    red[w][lane] = acc4[0] + acc4[1] + acc4[2] + acc4[3];
    __syncthreads();
    if (t < 64)
      sS[t >> 4][t & 15] = red[0][t] + red[1][t] + red[2][t] + red[3][t];
    __syncthreads();

    // ---- phase B: h = relu(sS @ G + b1) -> bf16 (k1b structure, sS local)
#pragma unroll
    for (int half = 0; half < 2; ++half) {
      const int col = half * 2048 + t * 8;
      const f32x8 bv = *(const f32x8*)(b1 + col);
      f32x8 a0 = bv, a1 = bv, a2 = bv, a3 = bv;
#pragma unroll
      for (int rr = 0; rr < 16; ++rr) {
        const f32x8 g8 = *(const f32x8*)(G + (size_t)rr * NN + col);
        a0 += sS[0][rr] * g8;
        a1 += sS[1][rr] * g8;
        a2 += sS[2][rr] * g8;
        a3 += sS[3][rr] * g8;
      }
#define STORE_ROW(jj, av) {                                          \
      bf16x8 o;                                                      \
      _Pragma("unroll")                                              \
      for (int j = 0; j < 8; ++j) o[j] = (bf16)fmaxf((av)[j], 0.f);  \
      *(bf16x8*)(hout + (size_t)(r0 + (jj)) * NN + col) = o; }
      STORE_ROW(0, a0) STORE_ROW(1, a1) STORE_ROW(2, a2) STORE_ROW(3, a3)
#undef STORE_ROW
    }
  } else {
    // ---- role w2t: W2t[o][n] = (bf16)W2[n][o]
    const int bid  = blockIdx.x - 2048;               // 0..4095
    const int kb   = (bid >> 6) * 64;
    const int ob   = (bid & 63) * 64;
    const int rowi = t >> 4;
    const int col4 = (t & 15) * 4;
#pragma unroll
    for (int p = 0; p < 4; ++p) {
      const f32x4 v = *(const f32x4*)(W2 + (size_t)(kb + p*16 + rowi) * KOUT + ob + col4);
      tile[p*16 + rowi][col4 + 0] = v[0];
      tile[p*16 + rowi][col4 + 1] = v[1];
      tile[p*16 + rowi][col4 + 2] = v[2];
      tile[p*16 + rowi][col4 + 3] = v[3];
    }
    __syncthreads();
    const int jj0 = t >> 4;
    const int ii4 = (t & 15) * 4;
#pragma unroll
    for (int p = 0; p < 4; ++p) {
      const int jj = p*16 + jj0;
      bf16x4 o;
      o[0] = (bf16)tile[ii4 + 0][jj];
      o[1] = (bf16)tile[ii4 + 1][jj];
      o[2] = (bf16)tile[ii4 + 2][jj];
      o[3] = (bf16)tile[ii4 + 3][jj];
      *(bf16x4*)(W2t + (size_t)(ob + jj) * NN + kb + ii4) = o;
    }
  }
}

// ---------------------------------------------------------------------------
// Kernel 3: 256x256 bf16 GEMM, 8 waves (2Mx4N), 2 barriers/K-tile.
// FROZEN R8/R10 version (207us, MfmaUtil 60%, 0 conflicts, VGPR 128).
#define NT 64   // K tiles = 4096/64

__global__ __launch_bounds__(512, 1) void k3_gemm256(
    const bf16* __restrict__ A, const bf16* __restrict__ Bt,
    const float* __restrict__ b2, float* __restrict__ C)
{
  extern __shared__ __align__(16) char smem[];
  bf16* lds = (bf16*)smem;
  const char* ldsc = (const char*)smem;

  // bijective XCD swizzle: 512 blocks, 512 % 8 == 0
  const int bid = blockIdx.x;
  const int swz = (bid & 7) * 64 + (bid >> 3);
  const int tm = swz >> 4, tn = swz & 15;       // 32 x 16 tiles
  const int brow = tm * 256, bcol = tn * 256;

  const int t    = threadIdx.x;
  const int lane = t & 63;
  const int wave = t >> 6;
  const int wr   = wave >> 2;   // 0..1  (M)
  const int wc   = wave & 3;    // 0..3  (N)
  const int fr   = lane & 15;
  const int fk   = lane >> 4;

  // staging source coords: linear LDS dest byte d holds logical byte
  // l = d ^ ((row&7)<<4)
  int srow[2], scol[2];
#pragma unroll
  for (int i = 0; i < 2; ++i) {
    const int d   = i * 8192 + t * 16;
    const int row = d >> 7;
    const int l   = d ^ ((row & 7) << 4);
    srow[i] = row;
    scol[i] = (l & 127) >> 1;
  }
  const bf16* gA0 = A  + (size_t)brow * NN;
  const bf16* gA1 = A  + (size_t)(brow + 128) * NN;
  const bf16* gB0 = Bt + (size_t)bcol * NN;
  const bf16* gB1 = Bt + (size_t)(bcol + 128) * NN;

  // A region elem offs: buf*16384 + half*8192 ; B adds 32768
  auto stage = [&](const bf16* g, int regionElem, int kt) {
#pragma unroll
    for (int i = 0; i < 2; ++i)
      gload_lds16(g + (size_t)srow[i] * NN + kt + scol[i],
                  lds + regionElem + i * 4096 + t * 8);
  };

  auto offA = [&](int mi, int kk) -> int {
    const int row = mi * 32 + wr * 16 + fr;
    const int b = row * 128 + kk * 64 + fk * 16;
    return b ^ ((row & 7) << 4);
  };
  auto offB = [&](int nj, int kk) -> int {
    const int row = nj * 64 + wc * 16 + fr;
    const int b = row * 128 + kk * 64 + fk * 16;
    return b ^ ((row & 7) << 4);
  };

  f32x4 acc[8][4];
#pragma unroll
  for (int m = 0; m < 8; ++m)
#pragma unroll
    for (int n = 0; n < 4; ++n) acc[m][n] = (f32x4){0.f,0.f,0.f,0.f};

  bf16x8 a[8], b0[4], b1[4];

  // ---- prologue: tile0 {A0,B0,B1,A1}, tile1 {A0,B0,B1}; then pre-read
  stage(gA0, 0,           0); stage(gB0, 32768,       0);
  stage(gB1, 32768+8192,  0); stage(gA1, 8192,        0);
  stage(gA0, 16384,       64); stage(gB0, 32768+16384, 64);
  stage(gB1, 32768+16384+8192, 64);
  asm volatile("s_waitcnt vmcnt(6)" ::: "memory");
  BARRIER();
#pragma unroll
  for (int mi = 0; mi < 4; ++mi)
#pragma unroll
    for (int kk = 0; kk < 2; ++kk)
      a[mi*2+kk] = *(const bf16x8*)(ldsc + offA(mi, kk));
#pragma unroll
  for (int nj = 0; nj < 2; ++nj)
#pragma unroll
    for (int kk = 0; kk < 2; ++kk)
      b0[nj*2+kk] = *(const bf16x8*)(ldsc + 65536 + offB(nj, kk));

#pragma unroll 1
  for (int u0 = 0; u0 < NT; u0 += 2) {
#pragma unroll
    for (int hi = 0; hi < 2; ++hi) {
      const int u   = u0 + hi;
      const int buf = hi;
      const int obuf = buf ^ 1;
      const char* pa  = ldsc + buf  * 32768;
      const char* pb  = ldsc + 65536 + buf  * 32768;
      const char* pan = ldsc + obuf * 32768;
      const char* pbn = ldsc + 65536 + obuf * 32768;

      // ==== P1 (no barrier): stage (u+1)A1 ; Q1 = Am0 x Bn0 ; read Bn1
      if (u < NT-1) stage(gA1, obuf*16384 + 8192, (u+1)*64);
      __builtin_amdgcn_s_setprio(1);
#pragma unroll
      for (int mi = 0; mi < 4; ++mi)
#pragma unroll
        for (int nj = 0; nj < 2; ++nj)
#pragma unroll
          for (int kk = 0; kk < 2; ++kk)
            acc[mi][nj] = __builtin_amdgcn_mfma_f32_16x16x32_bf16(
                a[mi*2+kk], b0[nj*2+kk], acc[mi][nj], 0, 0, 0);
#pragma unroll
      for (int nj = 0; nj < 2; ++nj)
#pragma unroll
        for (int kk = 0; kk < 2; ++kk)
          b1[nj*2+kk] = *(const bf16x8*)(pb + 16384 + offB(nj, kk));
      __builtin_amdgcn_s_setprio(0);

      // ==== P2: BARRIER ; stage (u+2)A0 ; Q2 = Am0 x Bn1 ; read Am1
      BARRIER();
      if (u < NT-2) stage(gA0, buf*16384, (u+2)*64);
      __builtin_amdgcn_s_setprio(1);
#pragma unroll
      for (int mi = 0; mi < 4; ++mi)
#pragma unroll
        for (int nj = 0; nj < 2; ++nj)
#pragma unroll
          for (int kk = 0; kk < 2; ++kk)
            acc[mi][2+nj] = __builtin_amdgcn_mfma_f32_16x16x32_bf16(
                a[mi*2+kk], b1[nj*2+kk], acc[mi][2+nj], 0, 0, 0);
#pragma unroll
      for (int mi = 0; mi < 4; ++mi)
#pragma unroll
        for (int kk = 0; kk < 2; ++kk)
          a[mi*2+kk] = *(const bf16x8*)(pa + 16384 + offA(mi, kk));
      __builtin_amdgcn_s_setprio(0);

      // ==== P3 (no barrier): stage (u+2)B0 ; Q3 = Am1 x Bn1
      if (u < NT-2) stage(gB0, 32768 + buf*16384, (u+2)*64);
      __builtin_amdgcn_s_setprio(1);
#pragma unroll
      for (int mi = 0; mi < 4; ++mi)
#pragma unroll
        for (int nj = 0; nj < 2; ++nj)
#pragma unroll
          for (int kk = 0; kk < 2; ++kk)
            acc[4+mi][2+nj] = __builtin_amdgcn_mfma_f32_16x16x32_bf16(
                a[mi*2+kk], b1[nj*2+kk], acc[4+mi][2+nj], 0, 0, 0);
      __builtin_amdgcn_s_setprio(0);

      // ==== P4: stage (u+2)B1 ; vmcnt ; BARRIER ; Q4 + next-tile pre-reads
      if (u < NT-2) stage(gB1, 32768 + buf*16384 + 8192, (u+2)*64);
      if (u < NT-2)       { asm volatile("s_waitcnt vmcnt(6)" ::: "memory"); }
      else if (u == NT-2) { asm volatile("s_waitcnt vmcnt(0)" ::: "memory"); }
      BARRIER();
      __builtin_amdgcn_s_setprio(1);
#pragma unroll
      for (int mi = 0; mi < 4; ++mi)
#pragma unroll
        for (int nj = 0; nj < 2; ++nj)
#pragma unroll
          for (int kk = 0; kk < 2; ++kk)
            acc[4+mi][nj] = __builtin_amdgcn_mfma_f32_16x16x32_bf16(
                a[mi*2+kk], b0[nj*2+kk], acc[4+mi][nj], 0, 0, 0);
      if (u < NT-1) {
#pragma unroll
        for (int mi = 0; mi < 4; ++mi)
#pragma unroll
          for (int kk = 0; kk < 2; ++kk)
            a[mi*2+kk] = *(const bf16x8*)(pan + offA(mi, kk));
#pragma unroll
        for (int nj = 0; nj < 2; ++nj)
#pragma unroll
          for (int kk = 0; kk < 2; ++kk)
            b0[nj*2+kk] = *(const bf16x8*)(pbn + offB(nj, kk));
      }
      __builtin_amdgcn_s_setprio(0);
    }
  }

  // epilogue: D layout col = fr, row = fk*4 + q
#pragma unroll
  for (int n = 0; n < 4; ++n) {
    const int col = bcol + n * 64 + wc * 16 + fr;
    const float bias = b2[col];
#pragma unroll
    for (int m = 0; m < 8; ++m) {
      const int row0 = brow + m * 32 + wr * 16 + fk * 4;
      float* cp = C + (size_t)row0 * KOUT + col;
#pragma unroll
      for (int q = 0; q < 4; ++q)
        cp[(size_t)q * KOUT] = acc[m][n][q] + bias;
    }
  }
}

// ---------------------------------------------------------------------------
extern "C" void kernel_launch(void* const* d_in, const int* in_sizes, int n_in,
                              void* d_out, int out_size, void* d_ws, size_t ws_size,
                              hipStream_t stream) {
  const float* x  = (const float*)d_in[0];
  const float* G  = (const float*)d_in[1];
  const float* H  = (const float*)d_in[2];
  const float* b1 = (const float*)d_in[3];
  const float* W2 = (const float*)d_in[4];
  const float* b2 = (const float*)d_in[5];
  float* y = (float*)d_out;

  bf16* hbuf = (bf16*)d_ws;                         // 8192*4096*2 = 64 MiB
  bf16* w2t  = hbuf + (size_t)MB * NN;              // 4096*4096*2 = 32 MiB

  hipFuncSetAttribute((const void*)k3_gemm256,
                      hipFuncAttributeMaxDynamicSharedMemorySize, 131072);

  hipLaunchKernelGGL(d_pre, dim3(2048 + 4096), dim3(256), 0, stream,
                     x, H, G, b1, hbuf, W2, w2t);
  hipLaunchKernelGGL(k3_gemm256, dim3((MB/256) * (KOUT/256)), dim3(512), 131072,
                     stream, hbuf, w2t, b2, y);
}

// Round 12
// 289.432 us; speedup vs baseline: 1.7563x; 1.7563x over previous
//
#include <hip/hip_runtime.h>
#include <hip/hip_bf16.h>
#include <cstdint>
#include <cstddef>

typedef __bf16 bf16;
typedef __bf16 bf16x4 __attribute__((ext_vector_type(4)));
typedef __bf16 bf16x8 __attribute__((ext_vector_type(8)));
typedef float  f32x4  __attribute__((ext_vector_type(4)));
typedef float  f32x8  __attribute__((ext_vector_type(8)));

#define MB   8192
#define NN   4096
#define RR   16
#define KOUT 4096

#define FENCE() asm volatile("" ::: "memory")
#define BARRIER() do { FENCE(); __builtin_amdgcn_s_barrier(); FENCE(); } while (0)

// ---------------------------------------------------------------------------
// async global->LDS (16B per lane). LDS dest: wave-uniform base + lane*16.
__device__ __forceinline__ void gload_lds16(const bf16* g, bf16* l) {
  __builtin_amdgcn_global_load_lds(
      (const __attribute__((address_space(1))) void*)g,
      (__attribute__((address_space(3))) void*)l, 16, 0, 0);
}

// ---------------------------------------------------------------------------
// W2 transpose-cast of one 64x64 tile (shared by d1/d2 roles).
__device__ __forceinline__ void w2t_tile(
    const float* __restrict__ W2, bf16* __restrict__ W2t,
    int kb, int ob, int t, float (*tile)[65])
{
  const int row  = t >> 4;
  const int col4 = (t & 15) * 4;
#pragma unroll
  for (int p = 0; p < 4; ++p) {
    const f32x4 v = *(const f32x4*)(W2 + (size_t)(kb + p*16 + row) * KOUT + ob + col4);
    tile[p*16 + row][col4 + 0] = v[0];
    tile[p*16 + row][col4 + 1] = v[1];
    tile[p*16 + row][col4 + 2] = v[2];
    tile[p*16 + row][col4 + 3] = v[3];
  }
  __syncthreads();
  const int jj0 = t >> 4;
  const int ii4 = (t & 15) * 4;
#pragma unroll
  for (int p = 0; p < 4; ++p) {
    const int jj = p*16 + jj0;
    bf16x4 o;
    o[0] = (bf16)tile[ii4 + 0][jj];
    o[1] = (bf16)tile[ii4 + 1][jj];
    o[2] = (bf16)tile[ii4 + 2][jj];
    o[3] = (bf16)tile[ii4 + 3][jj];
    *(bf16x4*)(W2t + (size_t)(ob + jj) * NN + kb + ii4) = o;
  }
}

// ---------------------------------------------------------------------------
// Dispatch 1: blocks [0,512) = xH = x@H^T (MFMA); blocks [512,2560) =
// W2t for kb-half 0 (kb tiles 0..31).  Packs x-read with W2-half stream.
__global__ __launch_bounds__(256) void d1_xh_w2tA(
    const float* __restrict__ x, const float* __restrict__ H,
    float* __restrict__ xH,
    const float* __restrict__ W2, bf16* __restrict__ W2t)
{
  __shared__ float red[4][64][4];
  __shared__ float tile[64][65];
  const int t = threadIdx.x;

  if (blockIdx.x < 512) {
    const int lane = t & 63, w = t >> 6;
    const int r0 = blockIdx.x * 16;
    const int fr = lane & 15, fk = lane >> 4;

    const float* xp = x + (size_t)(r0 + fr) * NN + w * 1024 + fk * 8;
    const float* hp = H + (size_t)fr * NN + w * 1024 + fk * 8;

    f32x4 acc = {0.f, 0.f, 0.f, 0.f};
#pragma unroll 4
    for (int c = 0; c < 32; ++c) {
      const f32x4 xa = *(const f32x4*)(xp + c * 32);
      const f32x4 xb = *(const f32x4*)(xp + c * 32 + 4);
      const f32x4 ha = *(const f32x4*)(hp + c * 32);
      const f32x4 hb = *(const f32x4*)(hp + c * 32 + 4);
      bf16x8 af, bfv;
#pragma unroll
      for (int j = 0; j < 4; ++j) {
        af[j] = (bf16)xa[j]; af[4 + j] = (bf16)xb[j];
        bfv[j] = (bf16)ha[j]; bfv[4 + j] = (bf16)hb[j];
      }
      acc = __builtin_amdgcn_mfma_f32_16x16x32_bf16(af, bfv, acc, 0, 0, 0);
    }
    *(f32x4*)&red[w][lane][0] = acc;
    __syncthreads();
    if (t < 64) {
      f32x4 s = *(const f32x4*)&red[0][t][0];
      s += *(const f32x4*)&red[1][t][0];
      s += *(const f32x4*)&red[2][t][0];
      s += *(const f32x4*)&red[3][t][0];
#pragma unroll
      for (int q = 0; q < 4; ++q)
        xH[(size_t)(r0 + (t >> 4) * 4 + q) * RR + (t & 15)] = s[q];
    }
  } else {
    const int bid = blockIdx.x - 512;                 // 0..2047
    const int kb  = (bid >> 6) * 64;                  // kb tiles 0..31
    const int ob  = (bid & 63) * 64;
    w2t_tile(W2, W2t, kb, ob, t, tile);
  }
}

// ---------------------------------------------------------------------------
// Dispatch 2: blocks [0,2048) = h = relu(xH@G + b1) (4 rows each);
// blocks [2048,4096) = W2t for kb-half 1 (kb tiles 32..63).
__global__ __launch_bounds__(256) void d2_h_w2tB(
    const float* __restrict__ xH, const float* __restrict__ G,
    const float* __restrict__ b1, bf16* __restrict__ hout,
    const float* __restrict__ W2, bf16* __restrict__ W2t)
{
  __shared__ float tile[64][65];
  const int t = threadIdx.x;

  if (blockIdx.x < 2048) {
    const int r0 = blockIdx.x * 4;

    float xh[4][16];
#pragma unroll
    for (int row = 0; row < 4; ++row)
#pragma unroll
      for (int j = 0; j < 16; j += 4)
        *(f32x4*)&xh[row][j] = *(const f32x4*)(xH + (size_t)(r0 + row) * RR + j);

#pragma unroll
    for (int half = 0; half < 2; ++half) {
      const int col = half * 2048 + t * 8;
      const f32x8 bv = *(const f32x8*)(b1 + col);
      f32x8 a0 = bv, a1 = bv, a2 = bv, a3 = bv;
#pragma unroll
      for (int r = 0; r < 16; ++r) {
        const f32x8 g8 = *(const f32x8*)(G + (size_t)r * NN + col);
        a0 += xh[0][r] * g8;
        a1 += xh[1][r] * g8;
        a2 += xh[2][r] * g8;
        a3 += xh[3][r] * g8;
      }
#define STORE_ROW(rr, av) {                                          \
      bf16x8 o;                                                      \
      _Pragma("unroll")                                              \
      for (int j = 0; j < 8; ++j) o[j] = (bf16)fmaxf((av)[j], 0.f);  \
      *(bf16x8*)(hout + (size_t)(r0 + (rr)) * NN + col) = o; }
      STORE_ROW(0, a0) STORE_ROW(1, a1) STORE_ROW(2, a2) STORE_ROW(3, a3)
#undef STORE_ROW
    }
  } else {
    const int bid = blockIdx.x - 2048;                // 0..2047
    const int kb  = ((bid >> 6) + 32) * 64;           // kb tiles 32..63
    const int ob  = (bid & 63) * 64;
    w2t_tile(W2, W2t, kb, ob, t, tile);
  }
}

// ---------------------------------------------------------------------------
// Kernel 3: 256x256 bf16 GEMM, 8 waves (2Mx4N), 2 barriers/K-tile.
// FROZEN R8/R10 version (207us, MfmaUtil 60%, 0 conflicts, VGPR 128).
#define NT 64   // K tiles = 4096/64

__global__ __launch_bounds__(512, 1) void k3_gemm256(
    const bf16* __restrict__ A, const bf16* __restrict__ Bt,
    const float* __restrict__ b2, float* __restrict__ C)
{
  extern __shared__ __align__(16) char smem[];
  bf16* lds = (bf16*)smem;
  const char* ldsc = (const char*)smem;

  // bijective XCD swizzle: 512 blocks, 512 % 8 == 0
  const int bid = blockIdx.x;
  const int swz = (bid & 7) * 64 + (bid >> 3);
  const int tm = swz >> 4, tn = swz & 15;       // 32 x 16 tiles
  const int brow = tm * 256, bcol = tn * 256;

  const int t    = threadIdx.x;
  const int lane = t & 63;
  const int wave = t >> 6;
  const int wr   = wave >> 2;   // 0..1  (M)
  const int wc   = wave & 3;    // 0..3  (N)
  const int fr   = lane & 15;
  const int fk   = lane >> 4;

  // staging source coords: linear LDS dest byte d holds logical byte
  // l = d ^ ((row&7)<<4)
  int srow[2], scol[2];
#pragma unroll
  for (int i = 0; i < 2; ++i) {
    const int d   = i * 8192 + t * 16;
    const int row = d >> 7;
    const int l   = d ^ ((row & 7) << 4);
    srow[i] = row;
    scol[i] = (l & 127) >> 1;
  }
  const bf16* gA0 = A  + (size_t)brow * NN;
  const bf16* gA1 = A  + (size_t)(brow + 128) * NN;
  const bf16* gB0 = Bt + (size_t)bcol * NN;
  const bf16* gB1 = Bt + (size_t)(bcol + 128) * NN;

  // A region elem offs: buf*16384 + half*8192 ; B adds 32768
  auto stage = [&](const bf16* g, int regionElem, int kt) {
#pragma unroll
    for (int i = 0; i < 2; ++i)
      gload_lds16(g + (size_t)srow[i] * NN + kt + scol[i],
                  lds + regionElem + i * 4096 + t * 8);
  };

  auto offA = [&](int mi, int kk) -> int {
    const int row = mi * 32 + wr * 16 + fr;
    const int b = row * 128 + kk * 64 + fk * 16;
    return b ^ ((row & 7) << 4);
  };
  auto offB = [&](int nj, int kk) -> int {
    const int row = nj * 64 + wc * 16 + fr;
    const int b = row * 128 + kk * 64 + fk * 16;
    return b ^ ((row & 7) << 4);
  };

  f32x4 acc[8][4];
#pragma unroll
  for (int m = 0; m < 8; ++m)
#pragma unroll
    for (int n = 0; n < 4; ++n) acc[m][n] = (f32x4){0.f,0.f,0.f,0.f};

  bf16x8 a[8], b0[4], b1[4];

  // ---- prologue: tile0 {A0,B0,B1,A1}, tile1 {A0,B0,B1}; then pre-read
  stage(gA0, 0,           0); stage(gB0, 32768,       0);
  stage(gB1, 32768+8192,  0); stage(gA1, 8192,        0);
  stage(gA0, 16384,       64); stage(gB0, 32768+16384, 64);
  stage(gB1, 32768+16384+8192, 64);
  asm volatile("s_waitcnt vmcnt(6)" ::: "memory");
  BARRIER();
#pragma unroll
  for (int mi = 0; mi < 4; ++mi)
#pragma unroll
    for (int kk = 0; kk < 2; ++kk)
      a[mi*2+kk] = *(const bf16x8*)(ldsc + offA(mi, kk));
#pragma unroll
  for (int nj = 0; nj < 2; ++nj)
#pragma unroll
    for (int kk = 0; kk < 2; ++kk)
      b0[nj*2+kk] = *(const bf16x8*)(ldsc + 65536 + offB(nj, kk));

#pragma unroll 1
  for (int u0 = 0; u0 < NT; u0 += 2) {
#pragma unroll
    for (int hi = 0; hi < 2; ++hi) {
      const int u   = u0 + hi;
      const int buf = hi;
      const int obuf = buf ^ 1;
      const char* pa  = ldsc + buf  * 32768;
      const char* pb  = ldsc + 65536 + buf  * 32768;
      const char* pan = ldsc + obuf * 32768;
      const char* pbn = ldsc + 65536 + obuf * 32768;

      // ==== P1 (no barrier): stage (u+1)A1 ; Q1 = Am0 x Bn0 ; read Bn1
      if (u < NT-1) stage(gA1, obuf*16384 + 8192, (u+1)*64);
      __builtin_amdgcn_s_setprio(1);
#pragma unroll
      for (int mi = 0; mi < 4; ++mi)
#pragma unroll
        for (int nj = 0; nj < 2; ++nj)
#pragma unroll
          for (int kk = 0; kk < 2; ++kk)
            acc[mi][nj] = __builtin_amdgcn_mfma_f32_16x16x32_bf16(
                a[mi*2+kk], b0[nj*2+kk], acc[mi][nj], 0, 0, 0);
#pragma unroll
      for (int nj = 0; nj < 2; ++nj)
#pragma unroll
        for (int kk = 0; kk < 2; ++kk)
          b1[nj*2+kk] = *(const bf16x8*)(pb + 16384 + offB(nj, kk));
      __builtin_amdgcn_s_setprio(0);

      // ==== P2: BARRIER ; stage (u+2)A0 ; Q2 = Am0 x Bn1 ; read Am1
      BARRIER();
      if (u < NT-2) stage(gA0, buf*16384, (u+2)*64);
      __builtin_amdgcn_s_setprio(1);
#pragma unroll
      for (int mi = 0; mi < 4; ++mi)
#pragma unroll
        for (int nj = 0; nj < 2; ++nj)
#pragma unroll
          for (int kk = 0; kk < 2; ++kk)
            acc[mi][2+nj] = __builtin_amdgcn_mfma_f32_16x16x32_bf16(
                a[mi*2+kk], b1[nj*2+kk], acc[mi][2+nj], 0, 0, 0);
#pragma unroll
      for (int mi = 0; mi < 4; ++mi)
#pragma unroll
        for (int kk = 0; kk < 2; ++kk)
          a[mi*2+kk] = *(const bf16x8*)(pa + 16384 + offA(mi, kk));
      __builtin_amdgcn_s_setprio(0);

      // ==== P3 (no barrier): stage (u+2)B0 ; Q3 = Am1 x Bn1
      if (u < NT-2) stage(gB0, 32768 + buf*16384, (u+2)*64);
      __builtin_amdgcn_s_setprio(1);
#pragma unroll
      for (int mi = 0; mi < 4; ++mi)
#pragma unroll
        for (int nj = 0; nj < 2; ++nj)
#pragma unroll
          for (int kk = 0; kk < 2; ++kk)
            acc[4+mi][2+nj] = __builtin_amdgcn_mfma_f32_16x16x32_bf16(
                a[mi*2+kk], b1[nj*2+kk], acc[4+mi][2+nj], 0, 0, 0);
      __builtin_amdgcn_s_setprio(0);

      // ==== P4: stage (u+2)B1 ; vmcnt ; BARRIER ; Q4 + next-tile pre-reads
      if (u < NT-2) stage(gB1, 32768 + buf*16384 + 8192, (u+2)*64);
      if (u < NT-2)       { asm volatile("s_waitcnt vmcnt(6)" ::: "memory"); }
      else if (u == NT-2) { asm volatile("s_waitcnt vmcnt(0)" ::: "memory"); }
      BARRIER();
      __builtin_amdgcn_s_setprio(1);
#pragma unroll
      for (int mi = 0; mi < 4; ++mi)
#pragma unroll
        for (int nj = 0; nj < 2; ++nj)
#pragma unroll
          for (int kk = 0; kk < 2; ++kk)
            acc[4+mi][nj] = __builtin_amdgcn_mfma_f32_16x16x32_bf16(
                a[mi*2+kk], b0[nj*2+kk], acc[4+mi][nj], 0, 0, 0);
      if (u < NT-1) {
#pragma unroll
        for (int mi = 0; mi < 4; ++mi)
#pragma unroll
          for (int kk = 0; kk < 2; ++kk)
            a[mi*2+kk] = *(const bf16x8*)(pan + offA(mi, kk));
#pragma unroll
        for (int nj = 0; nj < 2; ++nj)
#pragma unroll
          for (int kk = 0; kk < 2; ++kk)
            b0[nj*2+kk] = *(const bf16x8*)(pbn + offB(nj, kk));
      }
      __builtin_amdgcn_s_setprio(0);
    }
  }

  // epilogue: D layout col = fr, row = fk*4 + q
#pragma unroll
  for (int n = 0; n < 4; ++n) {
    const int col = bcol + n * 64 + wc * 16 + fr;
    const float bias = b2[col];
#pragma unroll
    for (int m = 0; m < 8; ++m) {
      const int row0 = brow + m * 32 + wr * 16 + fk * 4;
      float* cp = C + (size_t)row0 * KOUT + col;
#pragma unroll
      for (int q = 0; q < 4; ++q)
        cp[(size_t)q * KOUT] = acc[m][n][q] + bias;
    }
  }
}

// ---------------------------------------------------------------------------
extern "C" void kernel_launch(void* const* d_in, const int* in_sizes, int n_in,
                              void* d_out, int out_size, void* d_ws, size_t ws_size,
                              hipStream_t stream) {
  const float* x  = (const float*)d_in[0];
  const float* G  = (const float*)d_in[1];
  const float* H  = (const float*)d_in[2];
  const float* b1 = (const float*)d_in[3];
  const float* W2 = (const float*)d_in[4];
  const float* b2 = (const float*)d_in[5];
  float* y = (float*)d_out;

  bf16*  hbuf = (bf16*)d_ws;                         // 8192*4096*2 = 64 MiB
  bf16*  w2t  = hbuf + (size_t)MB * NN;              // 4096*4096*2 = 32 MiB
  float* xhb  = (float*)(w2t + (size_t)NN * KOUT);   // 8192*16*4 = 512 KiB

  hipFuncSetAttribute((const void*)k3_gemm256,
                      hipFuncAttributeMaxDynamicSharedMemorySize, 131072);

  hipLaunchKernelGGL(d1_xh_w2tA, dim3(512 + 2048), dim3(256), 0, stream,
                     x, H, xhb, W2, w2t);
  hipLaunchKernelGGL(d2_h_w2tB, dim3(2048 + 2048), dim3(256), 0, stream,
                     xhb, G, b1, hbuf, W2, w2t);
  hipLaunchKernelGGL(k3_gemm256, dim3((MB/256) * (KOUT/256)), dim3(512), 131072,
                     stream, hbuf, w2t, b2, y);
}

// Round 13
// 281.009 us; speedup vs baseline: 1.8089x; 1.0300x over previous
//
#include <hip/hip_runtime.h>
#include <hip/hip_bf16.h>
#include <cstdint>
#include <cstddef>

typedef __bf16 bf16;
typedef __bf16 bf16x4 __attribute__((ext_vector_type(4)));
typedef __bf16 bf16x8 __attribute__((ext_vector_type(8)));
typedef float  f32x4  __attribute__((ext_vector_type(4)));
typedef float  f32x8  __attribute__((ext_vector_type(8)));

#define MB   8192
#define NN   4096
#define RR   16
#define KOUT 4096

#define FENCE() asm volatile("" ::: "memory")
#define BARRIER() do { FENCE(); __builtin_amdgcn_s_barrier(); FENCE(); } while (0)

// ---------------------------------------------------------------------------
// async global->LDS (16B per lane). LDS dest: wave-uniform base + lane*16.
__device__ __forceinline__ void gload_lds16(const bf16* g, bf16* l) {
  __builtin_amdgcn_global_load_lds(
      (const __attribute__((address_space(1))) void*)g,
      (__attribute__((address_space(3))) void*)l, 16, 0, 0);
}

// ---------------------------------------------------------------------------
// W2 transpose-cast of one 64x64 tile (shared by d1/d2 roles).
__device__ __forceinline__ void w2t_tile(
    const float* __restrict__ W2, bf16* __restrict__ W2t,
    int kb, int ob, int t, float (*tile)[65])
{
  const int row  = t >> 4;
  const int col4 = (t & 15) * 4;
#pragma unroll
  for (int p = 0; p < 4; ++p) {
    const f32x4 v = *(const f32x4*)(W2 + (size_t)(kb + p*16 + row) * KOUT + ob + col4);
    tile[p*16 + row][col4 + 0] = v[0];
    tile[p*16 + row][col4 + 1] = v[1];
    tile[p*16 + row][col4 + 2] = v[2];
    tile[p*16 + row][col4 + 3] = v[3];
  }
  __syncthreads();
  const int jj0 = t >> 4;
  const int ii4 = (t & 15) * 4;
#pragma unroll
  for (int p = 0; p < 4; ++p) {
    const int jj = p*16 + jj0;
    bf16x4 o;
    o[0] = (bf16)tile[ii4 + 0][jj];
    o[1] = (bf16)tile[ii4 + 1][jj];
    o[2] = (bf16)tile[ii4 + 2][jj];
    o[3] = (bf16)tile[ii4 + 3][jj];
    *(bf16x4*)(W2t + (size_t)(ob + jj) * NN + kb + ii4) = o;
  }
}

// ---------------------------------------------------------------------------
// Dispatch 1: blocks [0,1024) = xH partials (K-split x2; block = 16 rows x
// 2048 K, MFMA); blocks [1024,3072) = W2t for kb-half 0.
__global__ __launch_bounds__(256) void d1_xh_w2tA(
    const float* __restrict__ x, const float* __restrict__ H,
    float* __restrict__ xH0, float* __restrict__ xH1,
    const float* __restrict__ W2, bf16* __restrict__ W2t)
{
  __shared__ float red[4][64][4];
  __shared__ float tile[64][65];
  const int t = threadIdx.x;

  if (blockIdx.x < 1024) {
    const int rg = blockIdx.x >> 1;       // row group 0..511
    const int kh = blockIdx.x & 1;        // K half
    const int r0 = rg * 16;
    const int lane = t & 63, w = t >> 6;
    const int fr = lane & 15, fk = lane >> 4;

    const float* xp = x + (size_t)(r0 + fr) * NN + kh * 2048 + w * 512 + fk * 8;
    const float* hp = H + (size_t)fr * NN + kh * 2048 + w * 512 + fk * 8;

    f32x4 acc = {0.f, 0.f, 0.f, 0.f};
#pragma unroll 4
    for (int c = 0; c < 16; ++c) {
      const f32x4 xa = *(const f32x4*)(xp + c * 32);
      const f32x4 xb = *(const f32x4*)(xp + c * 32 + 4);
      const f32x4 ha = *(const f32x4*)(hp + c * 32);
      const f32x4 hb = *(const f32x4*)(hp + c * 32 + 4);
      bf16x8 af, bfv;
#pragma unroll
      for (int j = 0; j < 4; ++j) {
        af[j] = (bf16)xa[j]; af[4 + j] = (bf16)xb[j];
        bfv[j] = (bf16)ha[j]; bfv[4 + j] = (bf16)hb[j];
      }
      acc = __builtin_amdgcn_mfma_f32_16x16x32_bf16(af, bfv, acc, 0, 0, 0);
    }
    *(f32x4*)&red[w][lane][0] = acc;
    __syncthreads();
    if (t < 64) {
      f32x4 s = *(const f32x4*)&red[0][t][0];
      s += *(const f32x4*)&red[1][t][0];
      s += *(const f32x4*)&red[2][t][0];
      s += *(const f32x4*)&red[3][t][0];
      float* xO = kh ? xH1 : xH0;
#pragma unroll
      for (int q = 0; q < 4; ++q)
        xO[(size_t)(r0 + (t >> 4) * 4 + q) * RR + (t & 15)] = s[q];
    }
  } else {
    const int bid = blockIdx.x - 1024;                // 0..2047
    const int kb  = (bid >> 6) * 64;                  // kb tiles 0..31
    const int ob  = (bid & 63) * 64;
    w2t_tile(W2, W2t, kb, ob, t, tile);
  }
}

// ---------------------------------------------------------------------------
// Dispatch 2: blocks [0,2048) = h = relu((xH0+xH1)@G + b1) (4 rows each);
// blocks [2048,4096) = W2t for kb-half 1.
__global__ __launch_bounds__(256) void d2_h_w2tB(
    const float* __restrict__ xH0, const float* __restrict__ xH1,
    const float* __restrict__ G, const float* __restrict__ b1,
    bf16* __restrict__ hout,
    const float* __restrict__ W2, bf16* __restrict__ W2t)
{
  __shared__ float tile[64][65];
  const int t = threadIdx.x;

  if (blockIdx.x < 2048) {
    const int r0 = blockIdx.x * 4;

    float xh[4][16];
#pragma unroll
    for (int row = 0; row < 4; ++row)
#pragma unroll
      for (int j = 0; j < 16; j += 4) {
        const size_t off = (size_t)(r0 + row) * RR + j;
        const f32x4 v0 = *(const f32x4*)(xH0 + off);
        const f32x4 v1 = *(const f32x4*)(xH1 + off);
        *(f32x4*)&xh[row][j] = v0 + v1;
      }

#pragma unroll
    for (int half = 0; half < 2; ++half) {
      const int col = half * 2048 + t * 8;
      const f32x8 bv = *(const f32x8*)(b1 + col);
      f32x8 a0 = bv, a1 = bv, a2 = bv, a3 = bv;
#pragma unroll
      for (int r = 0; r < 16; ++r) {
        const f32x8 g8 = *(const f32x8*)(G + (size_t)r * NN + col);
        a0 += xh[0][r] * g8;
        a1 += xh[1][r] * g8;
        a2 += xh[2][r] * g8;
        a3 += xh[3][r] * g8;
      }
#define STORE_ROW(rr, av) {                                          \
      bf16x8 o;                                                      \
      _Pragma("unroll")                                              \
      for (int j = 0; j < 8; ++j) o[j] = (bf16)fmaxf((av)[j], 0.f);  \
      *(bf16x8*)(hout + (size_t)(r0 + (rr)) * NN + col) = o; }
      STORE_ROW(0, a0) STORE_ROW(1, a1) STORE_ROW(2, a2) STORE_ROW(3, a3)
#undef STORE_ROW
    }
  } else {
    const int bid = blockIdx.x - 2048;                // 0..2047
    const int kb  = ((bid >> 6) + 32) * 64;           // kb tiles 32..63
    const int ob  = (bid & 63) * 64;
    w2t_tile(W2, W2t, kb, ob, t, tile);
  }
}

// ---------------------------------------------------------------------------
// Kernel 3: 256x256 bf16 GEMM, 8 waves (2Mx4N), 2 barriers/K-tile.
// FROZEN R8/R10/R12 version (207us, MfmaUtil 60%, 0 conflicts, VGPR 128).
#define NT 64   // K tiles = 4096/64

__global__ __launch_bounds__(512, 1) void k3_gemm256(
    const bf16* __restrict__ A, const bf16* __restrict__ Bt,
    const float* __restrict__ b2, float* __restrict__ C)
{
  extern __shared__ __align__(16) char smem[];
  bf16* lds = (bf16*)smem;
  const char* ldsc = (const char*)smem;

  // bijective XCD swizzle: 512 blocks, 512 % 8 == 0
  const int bid = blockIdx.x;
  const int swz = (bid & 7) * 64 + (bid >> 3);
  const int tm = swz >> 4, tn = swz & 15;       // 32 x 16 tiles
  const int brow = tm * 256, bcol = tn * 256;

  const int t    = threadIdx.x;
  const int lane = t & 63;
  const int wave = t >> 6;
  const int wr   = wave >> 2;   // 0..1  (M)
  const int wc   = wave & 3;    // 0..3  (N)
  const int fr   = lane & 15;
  const int fk   = lane >> 4;

  // staging source coords: linear LDS dest byte d holds logical byte
  // l = d ^ ((row&7)<<4)
  int srow[2], scol[2];
#pragma unroll
  for (int i = 0; i < 2; ++i) {
    const int d   = i * 8192 + t * 16;
    const int row = d >> 7;
    const int l   = d ^ ((row & 7) << 4);
    srow[i] = row;
    scol[i] = (l & 127) >> 1;
  }
  const bf16* gA0 = A  + (size_t)brow * NN;
  const bf16* gA1 = A  + (size_t)(brow + 128) * NN;
  const bf16* gB0 = Bt + (size_t)bcol * NN;
  const bf16* gB1 = Bt + (size_t)(bcol + 128) * NN;

  // A region elem offs: buf*16384 + half*8192 ; B adds 32768
  auto stage = [&](const bf16* g, int regionElem, int kt) {
#pragma unroll
    for (int i = 0; i < 2; ++i)
      gload_lds16(g + (size_t)srow[i] * NN + kt + scol[i],
                  lds + regionElem + i * 4096 + t * 8);
  };

  auto offA = [&](int mi, int kk) -> int {
    const int row = mi * 32 + wr * 16 + fr;
    const int b = row * 128 + kk * 64 + fk * 16;
    return b ^ ((row & 7) << 4);
  };
  auto offB = [&](int nj, int kk) -> int {
    const int row = nj * 64 + wc * 16 + fr;
    const int b = row * 128 + kk * 64 + fk * 16;
    return b ^ ((row & 7) << 4);
  };

  f32x4 acc[8][4];
#pragma unroll
  for (int m = 0; m < 8; ++m)
#pragma unroll
    for (int n = 0; n < 4; ++n) acc[m][n] = (f32x4){0.f,0.f,0.f,0.f};

  bf16x8 a[8], b0[4], b1[4];

  // ---- prologue: tile0 {A0,B0,B1,A1}, tile1 {A0,B0,B1}; then pre-read
  stage(gA0, 0,           0); stage(gB0, 32768,       0);
  stage(gB1, 32768+8192,  0); stage(gA1, 8192,        0);
  stage(gA0, 16384,       64); stage(gB0, 32768+16384, 64);
  stage(gB1, 32768+16384+8192, 64);
  asm volatile("s_waitcnt vmcnt(6)" ::: "memory");
  BARRIER();
#pragma unroll
  for (int mi = 0; mi < 4; ++mi)
#pragma unroll
    for (int kk = 0; kk < 2; ++kk)
      a[mi*2+kk] = *(const bf16x8*)(ldsc + offA(mi, kk));
#pragma unroll
  for (int nj = 0; nj < 2; ++nj)
#pragma unroll
    for (int kk = 0; kk < 2; ++kk)
      b0[nj*2+kk] = *(const bf16x8*)(ldsc + 65536 + offB(nj, kk));

#pragma unroll 1
  for (int u0 = 0; u0 < NT; u0 += 2) {
#pragma unroll
    for (int hi = 0; hi < 2; ++hi) {
      const int u   = u0 + hi;
      const int buf = hi;
      const int obuf = buf ^ 1;
      const char* pa  = ldsc + buf  * 32768;
      const char* pb  = ldsc + 65536 + buf  * 32768;
      const char* pan = ldsc + obuf * 32768;
      const char* pbn = ldsc + 65536 + obuf * 32768;

      // ==== P1 (no barrier): stage (u+1)A1 ; Q1 = Am0 x Bn0 ; read Bn1
      if (u < NT-1) stage(gA1, obuf*16384 + 8192, (u+1)*64);
      __builtin_amdgcn_s_setprio(1);
#pragma unroll
      for (int mi = 0; mi < 4; ++mi)
#pragma unroll
        for (int nj = 0; nj < 2; ++nj)
#pragma unroll
          for (int kk = 0; kk < 2; ++kk)
            acc[mi][nj] = __builtin_amdgcn_mfma_f32_16x16x32_bf16(
                a[mi*2+kk], b0[nj*2+kk], acc[mi][nj], 0, 0, 0);
#pragma unroll
      for (int nj = 0; nj < 2; ++nj)
#pragma unroll
        for (int kk = 0; kk < 2; ++kk)
          b1[nj*2+kk] = *(const bf16x8*)(pb + 16384 + offB(nj, kk));
      __builtin_amdgcn_s_setprio(0);

      // ==== P2: BARRIER ; stage (u+2)A0 ; Q2 = Am0 x Bn1 ; read Am1
      BARRIER();
      if (u < NT-2) stage(gA0, buf*16384, (u+2)*64);
      __builtin_amdgcn_s_setprio(1);
#pragma unroll
      for (int mi = 0; mi < 4; ++mi)
#pragma unroll
        for (int nj = 0; nj < 2; ++nj)
#pragma unroll
          for (int kk = 0; kk < 2; ++kk)
            acc[mi][2+nj] = __builtin_amdgcn_mfma_f32_16x16x32_bf16(
                a[mi*2+kk], b1[nj*2+kk], acc[mi][2+nj], 0, 0, 0);
#pragma unroll
      for (int mi = 0; mi < 4; ++mi)
#pragma unroll
        for (int kk = 0; kk < 2; ++kk)
          a[mi*2+kk] = *(const bf16x8*)(pa + 16384 + offA(mi, kk));
      __builtin_amdgcn_s_setprio(0);

      // ==== P3 (no barrier): stage (u+2)B0 ; Q3 = Am1 x Bn1
      if (u < NT-2) stage(gB0, 32768 + buf*16384, (u+2)*64);
      __builtin_amdgcn_s_setprio(1);
#pragma unroll
      for (int mi = 0; mi < 4; ++mi)
#pragma unroll
        for (int nj = 0; nj < 2; ++nj)
#pragma unroll
          for (int kk = 0; kk < 2; ++kk)
            acc[4+mi][2+nj] = __builtin_amdgcn_mfma_f32_16x16x32_bf16(
                a[mi*2+kk], b1[nj*2+kk], acc[4+mi][2+nj], 0, 0, 0);
      __builtin_amdgcn_s_setprio(0);

      // ==== P4: stage (u+2)B1 ; vmcnt ; BARRIER ; Q4 + next-tile pre-reads
      if (u < NT-2) stage(gB1, 32768 + buf*16384 + 8192, (u+2)*64);
      if (u < NT-2)       { asm volatile("s_waitcnt vmcnt(6)" ::: "memory"); }
      else if (u == NT-2) { asm volatile("s_waitcnt vmcnt(0)" ::: "memory"); }
      BARRIER();
      __builtin_amdgcn_s_setprio(1);
#pragma unroll
      for (int mi = 0; mi < 4; ++mi)
#pragma unroll
        for (int nj = 0; nj < 2; ++nj)
#pragma unroll
          for (int kk = 0; kk < 2; ++kk)
            acc[4+mi][nj] = __builtin_amdgcn_mfma_f32_16x16x32_bf16(
                a[mi*2+kk], b0[nj*2+kk], acc[4+mi][nj], 0, 0, 0);
      if (u < NT-1) {
#pragma unroll
        for (int mi = 0; mi < 4; ++mi)
#pragma unroll
          for (int kk = 0; kk < 2; ++kk)
            a[mi*2+kk] = *(const bf16x8*)(pan + offA(mi, kk));
#pragma unroll
        for (int nj = 0; nj < 2; ++nj)
#pragma unroll
          for (int kk = 0; kk < 2; ++kk)
            b0[nj*2+kk] = *(const bf16x8*)(pbn + offB(nj, kk));
      }
      __builtin_amdgcn_s_setprio(0);
    }
  }

  // epilogue: D layout col = fr, row = fk*4 + q
#pragma unroll
  for (int n = 0; n < 4; ++n) {
    const int col = bcol + n * 64 + wc * 16 + fr;
    const float bias = b2[col];
#pragma unroll
    for (int m = 0; m < 8; ++m) {
      const int row0 = brow + m * 32 + wr * 16 + fk * 4;
      float* cp = C + (size_t)row0 * KOUT + col;
#pragma unroll
      for (int q = 0; q < 4; ++q)
        cp[(size_t)q * KOUT] = acc[m][n][q] + bias;
    }
  }
}

// ---------------------------------------------------------------------------
extern "C" void kernel_launch(void* const* d_in, const int* in_sizes, int n_in,
                              void* d_out, int out_size, void* d_ws, size_t ws_size,
                              hipStream_t stream) {
  const float* x  = (const float*)d_in[0];
  const float* G  = (const float*)d_in[1];
  const float* H  = (const float*)d_in[2];
  const float* b1 = (const float*)d_in[3];
  const float* W2 = (const float*)d_in[4];
  const float* b2 = (const float*)d_in[5];
  float* y = (float*)d_out;

  bf16*  hbuf = (bf16*)d_ws;                         // 8192*4096*2 = 64 MiB
  bf16*  w2t  = hbuf + (size_t)MB * NN;              // 4096*4096*2 = 32 MiB
  float* xh0  = (float*)(w2t + (size_t)NN * KOUT);   // 8192*16*4 = 512 KiB
  float* xh1  = xh0 + (size_t)MB * RR;               // 512 KiB

  hipFuncSetAttribute((const void*)k3_gemm256,
                      hipFuncAttributeMaxDynamicSharedMemorySize, 131072);

  hipLaunchKernelGGL(d1_xh_w2tA, dim3(1024 + 2048), dim3(256), 0, stream,
                     x, H, xh0, xh1, W2, w2t);
  hipLaunchKernelGGL(d2_h_w2tB, dim3(2048 + 2048), dim3(256), 0, stream,
                     xh0, xh1, G, b1, hbuf, W2, w2t);
  hipLaunchKernelGGL(k3_gemm256, dim3((MB/256) * (KOUT/256)), dim3(512), 131072,
                     stream, hbuf, w2t, b2, y);
}

// Round 14
// 280.239 us; speedup vs baseline: 1.8139x; 1.0027x over previous
//
#include <hip/hip_runtime.h>
#include <hip/hip_bf16.h>
#include <cstdint>
#include <cstddef>

typedef __bf16 bf16;
typedef __bf16 bf16x4 __attribute__((ext_vector_type(4)));
typedef __bf16 bf16x8 __attribute__((ext_vector_type(8)));
typedef float  f32x4  __attribute__((ext_vector_type(4)));
typedef float  f32x8  __attribute__((ext_vector_type(8)));

#define MB   8192
#define NN   4096
#define RR   16
#define KOUT 4096

// w2t kb-tile split between d1/d2 (balance: d1 has the 128MB x-read)
#define KB_D1 19
#define KB_D2 (64 - KB_D1)

#define FENCE() asm volatile("" ::: "memory")
#define BARRIER() do { FENCE(); __builtin_amdgcn_s_barrier(); FENCE(); } while (0)

// ---------------------------------------------------------------------------
// async global->LDS (16B per lane). LDS dest: wave-uniform base + lane*16.
__device__ __forceinline__ void gload_lds16(const bf16* g, bf16* l) {
  __builtin_amdgcn_global_load_lds(
      (const __attribute__((address_space(1))) void*)g,
      (__attribute__((address_space(3))) void*)l, 16, 0, 0);
}

// ---------------------------------------------------------------------------
// W2 transpose-cast of one 64x64 tile (shared by d1/d2 roles).
__device__ __forceinline__ void w2t_tile(
    const float* __restrict__ W2, bf16* __restrict__ W2t,
    int kb, int ob, int t, float (*tile)[65])
{
  const int row  = t >> 4;
  const int col4 = (t & 15) * 4;
#pragma unroll
  for (int p = 0; p < 4; ++p) {
    const f32x4 v = *(const f32x4*)(W2 + (size_t)(kb + p*16 + row) * KOUT + ob + col4);
    tile[p*16 + row][col4 + 0] = v[0];
    tile[p*16 + row][col4 + 1] = v[1];
    tile[p*16 + row][col4 + 2] = v[2];
    tile[p*16 + row][col4 + 3] = v[3];
  }
  __syncthreads();
  const int jj0 = t >> 4;
  const int ii4 = (t & 15) * 4;
#pragma unroll
  for (int p = 0; p < 4; ++p) {
    const int jj = p*16 + jj0;
    bf16x4 o;
    o[0] = (bf16)tile[ii4 + 0][jj];
    o[1] = (bf16)tile[ii4 + 1][jj];
    o[2] = (bf16)tile[ii4 + 2][jj];
    o[3] = (bf16)tile[ii4 + 3][jj];
    *(bf16x4*)(W2t + (size_t)(ob + jj) * NN + kb + ii4) = o;
  }
}

// ---------------------------------------------------------------------------
// Dispatch 1: blocks [0,1024) = xH partials (K-split x2; block = 16 rows x
// 2048 K, MFMA); blocks [1024,1024+KB_D1*64) = W2t kb tiles [0,KB_D1).
__global__ __launch_bounds__(256) void d1_xh_w2tA(
    const float* __restrict__ x, const float* __restrict__ H,
    float* __restrict__ xH0, float* __restrict__ xH1,
    const float* __restrict__ W2, bf16* __restrict__ W2t)
{
  __shared__ float red[4][64][4];
  __shared__ float tile[64][65];
  const int t = threadIdx.x;

  if (blockIdx.x < 1024) {
    const int rg = blockIdx.x >> 1;       // row group 0..511
    const int kh = blockIdx.x & 1;        // K half
    const int r0 = rg * 16;
    const int lane = t & 63, w = t >> 6;
    const int fr = lane & 15, fk = lane >> 4;

    const float* xp = x + (size_t)(r0 + fr) * NN + kh * 2048 + w * 512 + fk * 8;
    const float* hp = H + (size_t)fr * NN + kh * 2048 + w * 512 + fk * 8;

    f32x4 acc = {0.f, 0.f, 0.f, 0.f};
#pragma unroll 4
    for (int c = 0; c < 16; ++c) {
      const f32x4 xa = *(const f32x4*)(xp + c * 32);
      const f32x4 xb = *(const f32x4*)(xp + c * 32 + 4);
      const f32x4 ha = *(const f32x4*)(hp + c * 32);
      const f32x4 hb = *(const f32x4*)(hp + c * 32 + 4);
      bf16x8 af, bfv;
#pragma unroll
      for (int j = 0; j < 4; ++j) {
        af[j] = (bf16)xa[j]; af[4 + j] = (bf16)xb[j];
        bfv[j] = (bf16)ha[j]; bfv[4 + j] = (bf16)hb[j];
      }
      acc = __builtin_amdgcn_mfma_f32_16x16x32_bf16(af, bfv, acc, 0, 0, 0);
    }
    *(f32x4*)&red[w][lane][0] = acc;
    __syncthreads();
    if (t < 64) {
      f32x4 s = *(const f32x4*)&red[0][t][0];
      s += *(const f32x4*)&red[1][t][0];
      s += *(const f32x4*)&red[2][t][0];
      s += *(const f32x4*)&red[3][t][0];
      float* xO = kh ? xH1 : xH0;
#pragma unroll
      for (int q = 0; q < 4; ++q)
        xO[(size_t)(r0 + (t >> 4) * 4 + q) * RR + (t & 15)] = s[q];
    }
  } else {
    const int bid = blockIdx.x - 1024;                // 0..KB_D1*64-1
    const int kb  = (bid >> 6) * 64;                  // kb tiles 0..KB_D1-1
    const int ob  = (bid & 63) * 64;
    w2t_tile(W2, W2t, kb, ob, t, tile);
  }
}

// ---------------------------------------------------------------------------
// Dispatch 2: blocks [0,2048) = h = relu((xH0+xH1)@G + b1) (4 rows each);
// blocks [2048,2048+KB_D2*64) = W2t kb tiles [KB_D1,64).
__global__ __launch_bounds__(256) void d2_h_w2tB(
    const float* __restrict__ xH0, const float* __restrict__ xH1,
    const float* __restrict__ G, const float* __restrict__ b1,
    bf16* __restrict__ hout,
    const float* __restrict__ W2, bf16* __restrict__ W2t)
{
  __shared__ float tile[64][65];
  const int t = threadIdx.x;

  if (blockIdx.x < 2048) {
    const int r0 = blockIdx.x * 4;

    float xh[4][16];
#pragma unroll
    for (int row = 0; row < 4; ++row)
#pragma unroll
      for (int j = 0; j < 16; j += 4) {
        const size_t off = (size_t)(r0 + row) * RR + j;
        const f32x4 v0 = *(const f32x4*)(xH0 + off);
        const f32x4 v1 = *(const f32x4*)(xH1 + off);
        *(f32x4*)&xh[row][j] = v0 + v1;
      }

#pragma unroll
    for (int half = 0; half < 2; ++half) {
      const int col = half * 2048 + t * 8;
      const f32x8 bv = *(const f32x8*)(b1 + col);
      f32x8 a0 = bv, a1 = bv, a2 = bv, a3 = bv;
#pragma unroll
      for (int r = 0; r < 16; ++r) {
        const f32x8 g8 = *(const f32x8*)(G + (size_t)r * NN + col);
        a0 += xh[0][r] * g8;
        a1 += xh[1][r] * g8;
        a2 += xh[2][r] * g8;
        a3 += xh[3][r] * g8;
      }
#define STORE_ROW(rr, av) {                                          \
      bf16x8 o;                                                      \
      _Pragma("unroll")                                              \
      for (int j = 0; j < 8; ++j) o[j] = (bf16)fmaxf((av)[j], 0.f);  \
      *(bf16x8*)(hout + (size_t)(r0 + (rr)) * NN + col) = o; }
      STORE_ROW(0, a0) STORE_ROW(1, a1) STORE_ROW(2, a2) STORE_ROW(3, a3)
#undef STORE_ROW
    }
  } else {
    const int bid = blockIdx.x - 2048;                // 0..KB_D2*64-1
    const int kb  = ((bid >> 6) + KB_D1) * 64;        // kb tiles KB_D1..63
    const int ob  = (bid & 63) * 64;
    w2t_tile(W2, W2t, kb, ob, t, tile);
  }
}

// ---------------------------------------------------------------------------
// Kernel 3: 256x256 bf16 GEMM, 8 waves (2Mx4N), 2 barriers/K-tile.
// FROZEN R8/R10/R12 version (207us, MfmaUtil 60%, 0 conflicts, VGPR 128).
#define NT 64   // K tiles = 4096/64

__global__ __launch_bounds__(512, 1) void k3_gemm256(
    const bf16* __restrict__ A, const bf16* __restrict__ Bt,
    const float* __restrict__ b2, float* __restrict__ C)
{
  extern __shared__ __align__(16) char smem[];
  bf16* lds = (bf16*)smem;
  const char* ldsc = (const char*)smem;

  // bijective XCD swizzle: 512 blocks, 512 % 8 == 0
  const int bid = blockIdx.x;
  const int swz = (bid & 7) * 64 + (bid >> 3);
  const int tm = swz >> 4, tn = swz & 15;       // 32 x 16 tiles
  const int brow = tm * 256, bcol = tn * 256;

  const int t    = threadIdx.x;
  const int lane = t & 63;
  const int wave = t >> 6;
  const int wr   = wave >> 2;   // 0..1  (M)
  const int wc   = wave & 3;    // 0..3  (N)
  const int fr   = lane & 15;
  const int fk   = lane >> 4;

  // staging source coords: linear LDS dest byte d holds logical byte
  // l = d ^ ((row&7)<<4)
  int srow[2], scol[2];
#pragma unroll
  for (int i = 0; i < 2; ++i) {
    const int d   = i * 8192 + t * 16;
    const int row = d >> 7;
    const int l   = d ^ ((row & 7) << 4);
    srow[i] = row;
    scol[i] = (l & 127) >> 1;
  }
  const bf16* gA0 = A  + (size_t)brow * NN;
  const bf16* gA1 = A  + (size_t)(brow + 128) * NN;
  const bf16* gB0 = Bt + (size_t)bcol * NN;
  const bf16* gB1 = Bt + (size_t)(bcol + 128) * NN;

  // A region elem offs: buf*16384 + half*8192 ; B adds 32768
  auto stage = [&](const bf16* g, int regionElem, int kt) {
#pragma unroll
    for (int i = 0; i < 2; ++i)
      gload_lds16(g + (size_t)srow[i] * NN + kt + scol[i],
                  lds + regionElem + i * 4096 + t * 8);
  };

  auto offA = [&](int mi, int kk) -> int {
    const int row = mi * 32 + wr * 16 + fr;
    const int b = row * 128 + kk * 64 + fk * 16;
    return b ^ ((row & 7) << 4);
  };
  auto offB = [&](int nj, int kk) -> int {
    const int row = nj * 64 + wc * 16 + fr;
    const int b = row * 128 + kk * 64 + fk * 16;
    return b ^ ((row & 7) << 4);
  };

  f32x4 acc[8][4];
#pragma unroll
  for (int m = 0; m < 8; ++m)
#pragma unroll
    for (int n = 0; n < 4; ++n) acc[m][n] = (f32x4){0.f,0.f,0.f,0.f};

  bf16x8 a[8], b0[4], b1[4];

  // ---- prologue: tile0 {A0,B0,B1,A1}, tile1 {A0,B0,B1}; then pre-read
  stage(gA0, 0,           0); stage(gB0, 32768,       0);
  stage(gB1, 32768+8192,  0); stage(gA1, 8192,        0);
  stage(gA0, 16384,       64); stage(gB0, 32768+16384, 64);
  stage(gB1, 32768+16384+8192, 64);
  asm volatile("s_waitcnt vmcnt(6)" ::: "memory");
  BARRIER();
#pragma unroll
  for (int mi = 0; mi < 4; ++mi)
#pragma unroll
    for (int kk = 0; kk < 2; ++kk)
      a[mi*2+kk] = *(const bf16x8*)(ldsc + offA(mi, kk));
#pragma unroll
  for (int nj = 0; nj < 2; ++nj)
#pragma unroll
    for (int kk = 0; kk < 2; ++kk)
      b0[nj*2+kk] = *(const bf16x8*)(ldsc + 65536 + offB(nj, kk));

#pragma unroll 1
  for (int u0 = 0; u0 < NT; u0 += 2) {
#pragma unroll
    for (int hi = 0; hi < 2; ++hi) {
      const int u   = u0 + hi;
      const int buf = hi;
      const int obuf = buf ^ 1;
      const char* pa  = ldsc + buf  * 32768;
      const char* pb  = ldsc + 65536 + buf  * 32768;
      const char* pan = ldsc + obuf * 32768;
      const char* pbn = ldsc + 65536 + obuf * 32768;

      // ==== P1 (no barrier): stage (u+1)A1 ; Q1 = Am0 x Bn0 ; read Bn1
      if (u < NT-1) stage(gA1, obuf*16384 + 8192, (u+1)*64);
      __builtin_amdgcn_s_setprio(1);
#pragma unroll
      for (int mi = 0; mi < 4; ++mi)
#pragma unroll
        for (int nj = 0; nj < 2; ++nj)
#pragma unroll
          for (int kk = 0; kk < 2; ++kk)
            acc[mi][nj] = __builtin_amdgcn_mfma_f32_16x16x32_bf16(
                a[mi*2+kk], b0[nj*2+kk], acc[mi][nj], 0, 0, 0);
#pragma unroll
      for (int nj = 0; nj < 2; ++nj)
#pragma unroll
        for (int kk = 0; kk < 2; ++kk)
          b1[nj*2+kk] = *(const bf16x8*)(pb + 16384 + offB(nj, kk));
      __builtin_amdgcn_s_setprio(0);

      // ==== P2: BARRIER ; stage (u+2)A0 ; Q2 = Am0 x Bn1 ; read Am1
      BARRIER();
      if (u < NT-2) stage(gA0, buf*16384, (u+2)*64);
      __builtin_amdgcn_s_setprio(1);
#pragma unroll
      for (int mi = 0; mi < 4; ++mi)
#pragma unroll
        for (int nj = 0; nj < 2; ++nj)
#pragma unroll
          for (int kk = 0; kk < 2; ++kk)
            acc[mi][2+nj] = __builtin_amdgcn_mfma_f32_16x16x32_bf16(
                a[mi*2+kk], b1[nj*2+kk], acc[mi][2+nj], 0, 0, 0);
#pragma unroll
      for (int mi = 0; mi < 4; ++mi)
#pragma unroll
        for (int kk = 0; kk < 2; ++kk)
          a[mi*2+kk] = *(const bf16x8*)(pa + 16384 + offA(mi, kk));
      __builtin_amdgcn_s_setprio(0);

      // ==== P3 (no barrier): stage (u+2)B0 ; Q3 = Am1 x Bn1
      if (u < NT-2) stage(gB0, 32768 + buf*16384, (u+2)*64);
      __builtin_amdgcn_s_setprio(1);
#pragma unroll
      for (int mi = 0; mi < 4; ++mi)
#pragma unroll
        for (int nj = 0; nj < 2; ++nj)
#pragma unroll
          for (int kk = 0; kk < 2; ++kk)
            acc[4+mi][2+nj] = __builtin_amdgcn_mfma_f32_16x16x32_bf16(
                a[mi*2+kk], b1[nj*2+kk], acc[4+mi][2+nj], 0, 0, 0);
      __builtin_amdgcn_s_setprio(0);

      // ==== P4: stage (u+2)B1 ; vmcnt ; BARRIER ; Q4 + next-tile pre-reads
      if (u < NT-2) stage(gB1, 32768 + buf*16384 + 8192, (u+2)*64);
      if (u < NT-2)       { asm volatile("s_waitcnt vmcnt(6)" ::: "memory"); }
      else if (u == NT-2) { asm volatile("s_waitcnt vmcnt(0)" ::: "memory"); }
      BARRIER();
      __builtin_amdgcn_s_setprio(1);
#pragma unroll
      for (int mi = 0; mi < 4; ++mi)
#pragma unroll
        for (int nj = 0; nj < 2; ++nj)
#pragma unroll
          for (int kk = 0; kk < 2; ++kk)
            acc[4+mi][nj] = __builtin_amdgcn_mfma_f32_16x16x32_bf16(
                a[mi*2+kk], b0[nj*2+kk], acc[4+mi][nj], 0, 0, 0);
      if (u < NT-1) {
#pragma unroll
        for (int mi = 0; mi < 4; ++mi)
#pragma unroll
          for (int kk = 0; kk < 2; ++kk)
            a[mi*2+kk] = *(const bf16x8*)(pan + offA(mi, kk));
#pragma unroll
        for (int nj = 0; nj < 2; ++nj)
#pragma unroll
          for (int kk = 0; kk < 2; ++kk)
            b0[nj*2+kk] = *(const bf16x8*)(pbn + offB(nj, kk));
      }
      __builtin_amdgcn_s_setprio(0);
    }
  }

  // epilogue: D layout col = fr, row = fk*4 + q
#pragma unroll
  for (int n = 0; n < 4; ++n) {
    const int col = bcol + n * 64 + wc * 16 + fr;
    const float bias = b2[col];
#pragma unroll
    for (int m = 0; m < 8; ++m) {
      const int row0 = brow + m * 32 + wr * 16 + fk * 4;
      float* cp = C + (size_t)row0 * KOUT + col;
#pragma unroll
      for (int q = 0; q < 4; ++q)
        cp[(size_t)q * KOUT] = acc[m][n][q] + bias;
    }
  }
}

// ---------------------------------------------------------------------------
extern "C" void kernel_launch(void* const* d_in, const int* in_sizes, int n_in,
                              void* d_out, int out_size, void* d_ws, size_t ws_size,
                              hipStream_t stream) {
  const float* x  = (const float*)d_in[0];
  const float* G  = (const float*)d_in[1];
  const float* H  = (const float*)d_in[2];
  const float* b1 = (const float*)d_in[3];
  const float* W2 = (const float*)d_in[4];
  const float* b2 = (const float*)d_in[5];
  float* y = (float*)d_out;

  bf16*  hbuf = (bf16*)d_ws;                         // 8192*4096*2 = 64 MiB
  bf16*  w2t  = hbuf + (size_t)MB * NN;              // 4096*4096*2 = 32 MiB
  float* xh0  = (float*)(w2t + (size_t)NN * KOUT);   // 8192*16*4 = 512 KiB
  float* xh1  = xh0 + (size_t)MB * RR;               // 512 KiB

  hipFuncSetAttribute((const void*)k3_gemm256,
                      hipFuncAttributeMaxDynamicSharedMemorySize, 131072);

  hipLaunchKernelGGL(d1_xh_w2tA, dim3(1024 + KB_D1 * 64), dim3(256), 0, stream,
                     x, H, xh0, xh1, W2, w2t);
  hipLaunchKernelGGL(d2_h_w2tB, dim3(2048 + KB_D2 * 64), dim3(256), 0, stream,
                     xh0, xh1, G, b1, hbuf, W2, w2t);
  hipLaunchKernelGGL(k3_gemm256, dim3((MB/256) * (KOUT/256)), dim3(512), 131072,
                     stream, hbuf, w2t, b2, y);
}